// Round 8
// baseline (435.373 us; speedup 1.0000x reference)
//
#include <hip/hip_runtime.h>

// ---------------------------------------------------------------------------
// PointNet++ set-abstraction block on MI355X.
// B=8, N=4096, K=32, D=64; out [B,N,128] fp32.
//  - layer0 linear decomposition: h0_pre = R[j] - Q[n]
//  - BN training-mode stats via per-block partials + k_redg/k_fin finalize
//  - layers 1/2 as fp16 MFMA (16x16x32) with fp32 accum
//  - max over K commutes with monotone BN affine: store max&min of h2 only
//  - kNN selection: R7-proven chunked pair-insertion (+R14 full-range tau).
//  - R16: h1 STAGING. k_l1<true> writes pre-BN layer1 output as fp16
//    (h1p, 128MB: LDS tile -> coalesced 64B/thread stores). k_l2f drops the
//    duplicate BUILD_X1 gather + layer1 MFMA pass and instead streams h1p
//    (half8 coalesced), applies bn1 affine+relu in regs, layer2 unchanged.
//    Launcher checks ws_size; falls back to the R15-proven k_l1/k_l2 pair
//    if the workspace can't hold h1p (then behavior == R15 exactly).
//  - R16b: k_prep does 16 points/block (W0 17KB LDS stage amortized 4x);
//    per-point math bit-identical.
//  - R15: all BN partial reductions via k_redg(64 blocks) + k_fin<64>.
//  - R12: k_fin partial count is a COMPILE-TIME template bound.
//  - R11: stats0 fused into k_knn epilogue; p0big aliases Mmax.
// ---------------------------------------------------------------------------

using half4  = __attribute__((ext_vector_type(4))) _Float16;
using half8  = __attribute__((ext_vector_type(8))) _Float16;
using floatx4 = __attribute__((ext_vector_type(4))) float;

#define NB 8
#define NP 4096
#define NQ (NB*NP)          // 32768 points / queries
#define CNT_INV (1.0f/1048576.0f)   // 1/(B*N*K), exact power of two

// ---- workspace layout (bytes) ----
#define OFF_XYZ4  0ull
#define OFF_Q     (OFF_XYZ4 + (size_t)NQ*4*4)       // xyz4: x,y,z,|x|^2
#define OFF_R     (OFF_Q    + (size_t)NQ*64*4)
#define OFF_IDX   (OFF_R    + (size_t)NQ*64*4)
#define OFF_W1H   (OFF_IDX  + (size_t)NQ*32*4)
#define OFF_W2H   (OFF_W1H  + 4096*2)
#define OFF_P0    (OFF_W2H  + 8192*2)               // q0/q1/q2 reduced partials
#define OFF_P1    (OFF_P0   + (size_t)1024*128*4)
#define OFF_P2    (OFF_P1   + (size_t)1024*128*4)
#define OFF_PAR   (OFF_P2   + (size_t)1024*256*4)
#define OFF_MMAX  (OFF_PAR  + 512*4)
#define OFF_MMIN  (OFF_MMAX + (size_t)NQ*128*4)
#define OFF_H1    (OFF_MMIN + (size_t)NQ*128*4)     // fp16 h1_pre [NQ][32][64]
#define WS_NEED   (OFF_H1   + (size_t)NQ*32*64*2)
// p0big (8192*128 floats = 4MB) aliases Mmax: consumed by k_redg before k_l2
// writes Mmax. q0/q1/q2 live inside the P0 region.
#define OFF_P0BIG OFF_MMAX
#define OFF_Q0    OFF_P0
#define OFF_Q1    (OFF_P0 + (size_t)64*128*4)
#define OFF_Q2    (OFF_P0 + (size_t)2*64*128*4)

// ---------------------------------------------------------------------------
// K0: per-point prep, 16 points/block (+ fused W1/W2 fp16 cast in trailing
// blocks). R16b: W0 LDS staging amortized over 16 points; math bit-identical.
// ---------------------------------------------------------------------------
__global__ __launch_bounds__(256) void k_prep(
    const float* __restrict__ xyz, const float* __restrict__ points,
    const float* __restrict__ W0, const float* __restrict__ b0,
    const float* __restrict__ W1, const float* __restrict__ W2,
    float* __restrict__ xyz4, float* __restrict__ Q, float* __restrict__ R,
    _Float16* __restrict__ W1h, _Float16* __restrict__ W2h) {
  if (blockIdx.x >= NQ/16) {   // fused k_cast
    int t = (blockIdx.x - NQ/16)*256 + threadIdx.x;
    if (t < 4096) W1h[t] = (_Float16)W1[t];
    if (t < 8192) W2h[t] = (_Float16)W2[t];
    return;
  }
  __shared__ float w0s[64*67];
  for (int i = threadIdx.x; i < 64*67; i += 256) w0s[i] = W0[i];
  __syncthreads();
  int o = threadIdx.x & 63;
  const float* wr = w0s + o*67;
  #pragma unroll
  for (int pl = 0; pl < 4; ++pl) {
    int p = blockIdx.x*16 + pl*4 + (threadIdx.x >> 6);
    float x = xyz[p*3+0], y = xyz[p*3+1], z = xyz[p*3+2];
    float q = wr[0]*x + wr[1]*y + wr[2]*z;
    float r = b0[o] + q;
    const float4* pp4 = (const float4*)(points + (size_t)p*64);
    #pragma unroll
    for (int c4 = 0; c4 < 16; ++c4) {
      float4 pv = pp4[c4];
      r = fmaf(wr[3+4*c4+0], pv.x, r);
      r = fmaf(wr[3+4*c4+1], pv.y, r);
      r = fmaf(wr[3+4*c4+2], pv.z, r);
      r = fmaf(wr[3+4*c4+3], pv.w, r);
    }
    Q[(size_t)p*64 + o] = q;
    R[(size_t)p*64 + o] = r;
    if (o == 0) {
      float sq = fmaf(x,x, fmaf(y,y, z*z));
      xyz4[p*4+0]=x; xyz4[p*4+1]=y; xyz4[p*4+2]=z; xyz4[p*4+3]=sq;
    }
  }
}

// ---------------------------------------------------------------------------
// K1: exact kNN (R7 selection, R14 full-range tau first) + fused stats0.
// ---------------------------------------------------------------------------
__device__ __forceinline__ unsigned fmap(float f) {
  unsigned u = __float_as_uint(f);
  return u ^ ((unsigned)((int)u >> 31) | 0x80000000u);
}

#define INSERT_ROUND(uu, jj)                                                  \
  {                                                                           \
    unsigned long long ball = __ballot((uu) <= utau && (uu) < thr);           \
    while (ball) {                                                            \
      int src = __ffsll(ball) - 1;                                            \
      ball &= ball - 1;                                                       \
      unsigned cu = (unsigned)__builtin_amdgcn_readlane((int)(uu), src);      \
      int cj = __builtin_amdgcn_readlane((jj), src);                          \
      if (cu < thr) {                                                         \
        unsigned long long m = __ballot(lane < 32 && ku < cu);                \
        int pos = __popcll(m);                                                \
        unsigned ku_up = __shfl_up(ku, 1);                                    \
        int jv_up = __shfl_up(jv, 1);                                         \
        if (lane < 32) {                                                      \
          if (lane > pos)      { ku = ku_up; jv = jv_up; }                    \
          else if (lane == pos){ ku = cu;    jv = cj;    }                    \
        }                                                                     \
        thr = (unsigned)__builtin_amdgcn_readlane((int)ku, 31);               \
      }                                                                       \
    }                                                                         \
  }

__global__ __launch_bounds__(256, 6) void k_knn(
    const float* __restrict__ xyz4, int* __restrict__ idxb,
    const float* __restrict__ R, const float* __restrict__ Q,
    float* __restrict__ p0) {
  const int lane = threadIdx.x & 63;
  const int w = threadIdx.x >> 6;
  const int qid = blockIdx.x * 4 + w;
  const int b = qid >> 12;
  const float4* xb = (const float4*)xyz4 + (size_t)b * NP;
  const float4 qv = xb[qid & (NP-1)];
  int* op = idxb + (size_t)qid * 32;

  // R14: min-only pass over chunks 32..63 FIRST (before dvA exists).
  float mn = __uint_as_float(0x7F800000u);
  {
    float mn1 = mn, mn2 = mn, mn3 = mn;
    #pragma unroll 4
    for (int c = 32; c < 64; c += 4) {
      float4 a0 = xb[(c+0)*64 + lane];
      float4 a1 = xb[(c+1)*64 + lane];
      float4 a2 = xb[(c+2)*64 + lane];
      float4 a3 = xb[(c+3)*64 + lane];
      float d0 = fmaf(-2.0f, fmaf(qv.x,a0.x, fmaf(qv.y,a0.y, qv.z*a0.z)), qv.w + a0.w);
      float d1 = fmaf(-2.0f, fmaf(qv.x,a1.x, fmaf(qv.y,a1.y, qv.z*a1.z)), qv.w + a1.w);
      float d2 = fmaf(-2.0f, fmaf(qv.x,a2.x, fmaf(qv.y,a2.y, qv.z*a2.z)), qv.w + a2.w);
      float d3 = fmaf(-2.0f, fmaf(qv.x,a3.x, fmaf(qv.y,a3.y, qv.z*a3.z)), qv.w + a3.w);
      mn = fminf(mn, d0); mn1 = fminf(mn1, d1);
      mn2 = fminf(mn2, d2); mn3 = fminf(mn3, d3);
    }
    mn = fminf(fminf(mn, mn1), fminf(mn2, mn3));
  }

  float dvA[32];
  #pragma unroll
  for (int c = 0; c < 32; ++c) {
    float4 cd = xb[c*64 + lane];
    float dot = fmaf(qv.x, cd.x, fmaf(qv.y, cd.y, qv.z*cd.z));
    float d   = fmaf(-2.0f, dot, qv.w + cd.w);
    dvA[c] = d;
    mn = fminf(mn, d);
  }

  const unsigned mu = fmap(mn);
  unsigned lo = 0u, hi = 0xFFFFFFFFu;
  for (int it = 0; it < 32; ++it) {
    unsigned mid = lo + ((hi - lo) >> 1);
    int cnt = __popcll(__ballot(mu <= mid));
    if (cnt >= 32) hi = mid; else lo = mid + 1;
  }
  const unsigned utau = hi;

  unsigned ku = 0xFFFFFFFFu;
  int jv = 0;
  unsigned thr = 0xFFFFFFFFu;
  #pragma unroll
  for (int c = 0; c < 32; ++c) {
    unsigned u = fmap(dvA[c]);
    int j = c*64 + lane;
    INSERT_ROUND(u, j)
  }
  #pragma unroll 8
  for (int c = 32; c < 64; ++c) {
    float4 cd = xb[c*64 + lane];
    float dot = fmaf(qv.x, cd.x, fmaf(qv.y, cd.y, qv.z*cd.z));
    float d   = fmaf(-2.0f, dot, qv.w + cd.w);
    unsigned u = fmap(d);
    int j = c*64 + lane;
    INSERT_ROUND(u, j)
  }
  if (lane < 32) op[lane] = jv;

  // ---- fused stats0 epilogue: v = R[j][c]-Q[qid][c], c = lane ----
  const float* Rb2 = R + (size_t)(qid & ~(NP-1))*64;
  const float  qc  = Q[(size_t)qid*64 + lane];
  float s = 0.f, ss = 0.f;
  #pragma unroll 8
  for (int k = 0; k < 32; ++k) {
    int j = __shfl(jv, k);                       // broadcast from lane k
    float v = Rb2[(size_t)j*64 + lane] - qc;     // coalesced 256B row
    s += v; ss = fmaf(v, v, ss);
  }
  __shared__ float red[4][128];
  red[w][lane]      = s;
  red[w][64 + lane] = ss;
  __syncthreads();
  if (w == 0) {
    float S  = red[0][lane]    + red[1][lane]    + red[2][lane]    + red[3][lane];
    float SS = red[0][64+lane] + red[1][64+lane] + red[2][64+lane] + red[3][64+lane];
    p0[(size_t)blockIdx.x*128 + lane]      = S;
    p0[(size_t)blockIdx.x*128 + 64 + lane] = SS;
  }
}

// ---------------------------------------------------------------------------
// K2b (R15): generic tree reduction of partial rows. 64 output rows.
// ---------------------------------------------------------------------------
template<int W, int RPB>
__global__ __launch_bounds__(256) void k_redg(
    const float* __restrict__ pin, float* __restrict__ pout) {
  constexpr int G   = 256 / W;   // thread groups per block
  constexpr int RPG = RPB / G;   // rows per group
  int r   = blockIdx.x;
  int col = threadIdx.x % W;
  int g   = threadIdx.x / W;
  const float* base = pin + ((size_t)r*RPB + (size_t)g*RPG)*W + col;
  float s = 0.f;
  #pragma unroll
  for (int i = 0; i < RPG; ++i) s += base[(size_t)i*W];
  if constexpr (G == 1) {
    pout[(size_t)r*W + col] = s;
  } else {
    __shared__ float rr[G][W];
    rr[g][col] = s;
    __syncthreads();
    if (threadIdx.x < W) {
      float t = rr[0][threadIdx.x];
      #pragma unroll
      for (int gg = 1; gg < G; ++gg) t += rr[gg][threadIdx.x];
      pout[(size_t)r*W + threadIdx.x] = t;
    }
  }
}

// ---------------------------------------------------------------------------
// K3: finalize BN stats -> affine params (scale, shift) at par[poff..].
// ---------------------------------------------------------------------------
template<int NPARTS>
__global__ void k_fin(const float* __restrict__ part, int C,
                      const float* __restrict__ g, const float* __restrict__ beta,
                      float* __restrict__ par, int poff) {
  int o = threadIdx.x;
  float S = 0.f, SS = 0.f;
  #pragma unroll
  for (int s = 0; s < NPARTS; ++s) {
    S  += part[s*2*C + o];
    SS += part[s*2*C + C + o];
  }
  float mu  = S * CNT_INV;
  float var = SS * CNT_INV - mu*mu;
  float sc  = g[o] * rsqrtf(var + 1e-5f);
  par[poff + o]     = sc;
  par[poff + C + o] = beta[o] - mu*sc;
}

// ---------------------------------------------------------------------------
// Phase-A helper macro: vectorized x1 build (float4 gather -> half4 LDS)
// ---------------------------------------------------------------------------
#define BUILD_X1(q0)                                                          \
  {                                                                           \
    int qid = (q0) + aql;                                                     \
    const float* Rb = R + (size_t)(qid & ~4095)*64;                           \
    const int* ix = idxb + (size_t)qid*32;                                    \
    float4 Q4 = ((const float4*)(Q + (size_t)qid*64))[aseg];                  \
    float qx = fmaf(-Q4.x, asc.x, ash.x);                                     \
    float qy = fmaf(-Q4.y, asc.y, ash.y);                                     \
    float qz = fmaf(-Q4.z, asc.z, ash.z);                                     \
    float qw = fmaf(-Q4.w, asc.w, ash.w);                                     \
    _Pragma("unroll")                                                         \
    for (int i = 0; i < 8; ++i) {                                             \
      int k = arg + (i<<2);                                                   \
      int j = ix[k];                                                          \
      float4 R4 = ((const float4*)(Rb + (size_t)j*64))[aseg];                 \
      float v0 = fmaxf(fmaf(R4.x, asc.x, qx), 0.f);                           \
      float v1 = fmaxf(fmaf(R4.y, asc.y, qy), 0.f);                           \
      float v2 = fmaxf(fmaf(R4.z, asc.z, qz), 0.f);                           \
      float v3 = fmaxf(fmaf(R4.w, asc.w, qw), 0.f);                           \
      half4 hv = {(_Float16)v0, (_Float16)v1, (_Float16)v2, (_Float16)v3};    \
      *(half4*)(x1 + (aql*32 + k)*72 + aseg*4) = hv;                          \
    }                                                                         \
  }

// ---------------------------------------------------------------------------
// K4: layer1 via fp16 MFMA; emit stats1 partials.
// STORE=true (R16): also stage h1_pre fp16 in LDS and stream it to h1p
// (coalesced 64B/thread) for k_l2f to consume.
// ---------------------------------------------------------------------------
template<bool STORE>
__global__ __launch_bounds__(256) void k_l1(
    const float* __restrict__ R, const float* __restrict__ Q,
    const int* __restrict__ idxb, const _Float16* __restrict__ W1h,
    const float* __restrict__ b1, const float* __restrict__ par,
    float* __restrict__ p1, _Float16* __restrict__ h1p) {
  __shared__ __align__(16) _Float16 x1[128*72];
  __shared__ __align__(16) _Float16 x2s[STORE ? 128*72 : 8];
  int o = threadIdx.x & 63, wg = threadIdx.x >> 6;
  int m16 = o & 15, quad = o >> 4;
  const int aql = threadIdx.x >> 6;
  const int arg = (threadIdx.x >> 4) & 3;
  const int aseg = threadIdx.x & 15;
  const float4 asc = ((const float4*)par)[aseg];
  const float4 ash = ((const float4*)(par+64))[aseg];
  int col = wg*16 + m16;
  half8 bf0 = *(const half8*)(W1h + col*64 + quad*8);
  half8 bf1 = *(const half8*)(W1h + col*64 + 32 + quad*8);
  float b1c = b1[col];
  float s = 0.f, ss = 0.f;

  for (int gi = 0; gi < 8; ++gi) {
    int q0 = (blockIdx.x*8 + gi) * 4;
    BUILD_X1(q0)
    __syncthreads();
    #pragma unroll
    for (int rt = 0; rt < 8; ++rt) {
      const _Float16* ap = x1 + (rt*16 + m16)*72 + quad*8;
      half8 a0 = *(const half8*)(ap);
      half8 a1 = *(const half8*)(ap + 32);
      floatx4 acc = {0.f,0.f,0.f,0.f};
      acc = __builtin_amdgcn_mfma_f32_16x16x32_f16(a0, bf0, acc, 0,0,0);
      acc = __builtin_amdgcn_mfma_f32_16x16x32_f16(a1, bf1, acc, 0,0,0);
      #pragma unroll
      for (int rg = 0; rg < 4; ++rg) {
        float h = acc[rg] + b1c;
        s += h; ss = fmaf(h, h, ss);
        if constexpr (STORE)
          x2s[(rt*16 + quad*4 + rg)*72 + col] = (_Float16)h;
      }
    }
    __syncthreads();   // x2s complete; x1 fully consumed
    if constexpr (STORE) {
      // coalesced copy-out: thread t -> row t>>1, half (t&1): 32 halfs = 64B
      int row = threadIdx.x >> 1, hs = threadIdx.x & 1;
      const float4* srcp = (const float4*)(x2s + (size_t)row*72 + hs*32);
      float4* dstp = (float4*)(h1p + ((size_t)q0*32 + (size_t)row)*64 + hs*32);
      #pragma unroll
      for (int i = 0; i < 4; ++i) dstp[i] = srcp[i];
      // next gi's first __syncthreads (after BUILD_X1) fences x2s reuse
    }
  }
  s  += __shfl_xor(s, 16);  s  += __shfl_xor(s, 32);
  ss += __shfl_xor(ss, 16); ss += __shfl_xor(ss, 32);
  if (quad == 0) {
    p1[blockIdx.x*128 + col]      = s;
    p1[blockIdx.x*128 + 64 + col] = ss;
  }
}

// ---------------------------------------------------------------------------
// K6f (R16): stream h1p -> bn1 affine+relu -> x2 LDS -> layer2 MFMA ->
// stats2 + max/min. No gather, no layer1 recompute, no x1 buffer.
// ---------------------------------------------------------------------------
__global__ __launch_bounds__(256) void k_l2f(
    const _Float16* __restrict__ h1p, const _Float16* __restrict__ W2h,
    const float* __restrict__ b2, const float* __restrict__ par,
    float* __restrict__ p2, float* __restrict__ Mmax, float* __restrict__ Mmin) {
  __shared__ __align__(16) _Float16 x2[128*72];
  int o = threadIdx.x & 63, wg = threadIdx.x >> 6;
  int m16 = o & 15, quad = o >> 4;
  // load/affine mapping: 8 fixed cols per thread, 4 rows (rb, rb+32, ...)
  const int c8 = (threadIdx.x & 7) * 8;
  const int rb = threadIdx.x >> 3;
  const float4 sc1a = *(const float4*)(par + 128 + c8);
  const float4 sc1b = *(const float4*)(par + 128 + c8 + 4);
  const float4 sh1a = *(const float4*)(par + 192 + c8);
  const float4 sh1b = *(const float4*)(par + 192 + c8 + 4);
  int colA = wg*16 + m16, colB = 64 + wg*16 + m16;
  half8 b2A0 = *(const half8*)(W2h + colA*64 + quad*8);
  half8 b2A1 = *(const half8*)(W2h + colA*64 + 32 + quad*8);
  half8 b2B0 = *(const half8*)(W2h + colB*64 + quad*8);
  half8 b2B1 = *(const half8*)(W2h + colB*64 + 32 + quad*8);
  float b2a = b2[colA], b2b = b2[colB];
  float sA=0.f, ssA=0.f, sB=0.f, ssB=0.f;

  for (int gi = 0; gi < 8; ++gi) {
    int q0 = (blockIdx.x*8 + gi) * 4;
    const _Float16* gsrc = h1p + (size_t)q0*2048;   // 32*64 halfs per query
    #pragma unroll
    for (int i = 0; i < 4; ++i) {
      int r = rb + 32*i;
      half8 hv = *(const half8*)(gsrc + (size_t)r*64 + c8);
      half8 ov;
      ov[0] = (_Float16)fmaxf(fmaf((float)hv[0], sc1a.x, sh1a.x), 0.f);
      ov[1] = (_Float16)fmaxf(fmaf((float)hv[1], sc1a.y, sh1a.y), 0.f);
      ov[2] = (_Float16)fmaxf(fmaf((float)hv[2], sc1a.z, sh1a.z), 0.f);
      ov[3] = (_Float16)fmaxf(fmaf((float)hv[3], sc1a.w, sh1a.w), 0.f);
      ov[4] = (_Float16)fmaxf(fmaf((float)hv[4], sc1b.x, sh1b.x), 0.f);
      ov[5] = (_Float16)fmaxf(fmaf((float)hv[5], sc1b.y, sh1b.y), 0.f);
      ov[6] = (_Float16)fmaxf(fmaf((float)hv[6], sc1b.z, sh1b.z), 0.f);
      ov[7] = (_Float16)fmaxf(fmaf((float)hv[7], sc1b.w, sh1b.w), 0.f);
      *(half8*)(x2 + (size_t)r*72 + c8) = ov;
    }
    __syncthreads();
    float mxA=0.f, mnA=0.f, mxB=0.f, mnB=0.f;
    #pragma unroll
    for (int rt = 0; rt < 8; ++rt) {
      const _Float16* ap = x2 + (rt*16 + m16)*72 + quad*8;
      half8 a0 = *(const half8*)(ap);
      half8 a1 = *(const half8*)(ap + 32);
      floatx4 accA = {0.f,0.f,0.f,0.f}, accB = {0.f,0.f,0.f,0.f};
      accA = __builtin_amdgcn_mfma_f32_16x16x32_f16(a0, b2A0, accA, 0,0,0);
      accA = __builtin_amdgcn_mfma_f32_16x16x32_f16(a1, b2A1, accA, 0,0,0);
      accB = __builtin_amdgcn_mfma_f32_16x16x32_f16(a0, b2B0, accB, 0,0,0);
      accB = __builtin_amdgcn_mfma_f32_16x16x32_f16(a1, b2B1, accB, 0,0,0);
      float hA0 = accA[0]+b2a, hA1 = accA[1]+b2a, hA2 = accA[2]+b2a, hA3 = accA[3]+b2a;
      float hB0 = accB[0]+b2b, hB1 = accB[1]+b2b, hB2 = accB[2]+b2b, hB3 = accB[3]+b2b;
      sA += hA0+hA1+hA2+hA3;
      ssA = fmaf(hA0,hA0, fmaf(hA1,hA1, fmaf(hA2,hA2, fmaf(hA3,hA3, ssA))));
      sB += hB0+hB1+hB2+hB3;
      ssB = fmaf(hB0,hB0, fmaf(hB1,hB1, fmaf(hB2,hB2, fmaf(hB3,hB3, ssB))));
      float m4A = fmaxf(fmaxf(hA0,hA1), fmaxf(hA2,hA3));
      float n4A = fminf(fminf(hA0,hA1), fminf(hA2,hA3));
      float m4B = fmaxf(fmaxf(hB0,hB1), fmaxf(hB2,hB3));
      float n4B = fminf(fminf(hB0,hB1), fminf(hB2,hB3));
      if ((rt & 1) == 0) { mxA=m4A; mnA=n4A; mxB=m4B; mnB=n4B; }
      else {
        mxA=fmaxf(mxA,m4A); mnA=fminf(mnA,n4A);
        mxB=fmaxf(mxB,m4B); mnB=fminf(mnB,n4B);
        mxA=fmaxf(mxA,__shfl_xor(mxA,16)); mxA=fmaxf(mxA,__shfl_xor(mxA,32));
        mnA=fminf(mnA,__shfl_xor(mnA,16)); mnA=fminf(mnA,__shfl_xor(mnA,32));
        mxB=fmaxf(mxB,__shfl_xor(mxB,16)); mxB=fmaxf(mxB,__shfl_xor(mxB,32));
        mnB=fminf(mnB,__shfl_xor(mnB,16)); mnB=fminf(mnB,__shfl_xor(mnB,32));
        if (quad == 0) {
          int qid = q0 + (rt >> 1);
          Mmax[(size_t)qid*128 + colA] = mxA;  Mmin[(size_t)qid*128 + colA] = mnA;
          Mmax[(size_t)qid*128 + colB] = mxB;  Mmin[(size_t)qid*128 + colB] = mnB;
        }
      }
    }
    __syncthreads();
  }
  sA += __shfl_xor(sA,16); sA += __shfl_xor(sA,32);
  ssA += __shfl_xor(ssA,16); ssA += __shfl_xor(ssA,32);
  sB += __shfl_xor(sB,16); sB += __shfl_xor(sB,32);
  ssB += __shfl_xor(ssB,16); ssB += __shfl_xor(ssB,32);
  if (quad == 0) {
    p2[blockIdx.x*256 + colA]        = sA;
    p2[blockIdx.x*256 + 128 + colA]  = ssA;
    p2[blockIdx.x*256 + colB]        = sB;
    p2[blockIdx.x*256 + 128 + colB]  = ssB;
  }
}

// ---------------------------------------------------------------------------
// K6 (fallback, R15-proven): layer1 recompute -> bn1+relu -> layer2 MFMA.
// ---------------------------------------------------------------------------
__global__ __launch_bounds__(256) void k_l2(
    const float* __restrict__ R, const float* __restrict__ Q,
    const int* __restrict__ idxb, const _Float16* __restrict__ W1h,
    const _Float16* __restrict__ W2h, const float* __restrict__ b1,
    const float* __restrict__ b2, const float* __restrict__ par,
    float* __restrict__ p2, float* __restrict__ Mmax, float* __restrict__ Mmin) {
  __shared__ __align__(16) _Float16 x1[128*72];
  __shared__ __align__(16) _Float16 x2[128*72];
  int o = threadIdx.x & 63, wg = threadIdx.x >> 6;
  int m16 = o & 15, quad = o >> 4;
  const int aql = threadIdx.x >> 6;
  const int arg = (threadIdx.x >> 4) & 3;
  const int aseg = threadIdx.x & 15;
  const float4 asc = ((const float4*)par)[aseg];
  const float4 ash = ((const float4*)(par+64))[aseg];
  int col1 = wg*16 + m16;
  float sc1 = par[128 + col1], sh1 = par[192 + col1];
  half8 b1f0 = *(const half8*)(W1h + col1*64 + quad*8);
  half8 b1f1 = *(const half8*)(W1h + col1*64 + 32 + quad*8);
  float b1c = b1[col1];
  int colA = wg*16 + m16, colB = 64 + wg*16 + m16;
  half8 b2A0 = *(const half8*)(W2h + colA*64 + quad*8);
  half8 b2A1 = *(const half8*)(W2h + colA*64 + 32 + quad*8);
  half8 b2B0 = *(const half8*)(W2h + colB*64 + quad*8);
  half8 b2B1 = *(const half8*)(W2h + colB*64 + 32 + quad*8);
  float b2a = b2[colA], b2b = b2[colB];
  float sA=0.f, ssA=0.f, sB=0.f, ssB=0.f;

  for (int gi = 0; gi < 8; ++gi) {
    int q0 = (blockIdx.x*8 + gi) * 4;
    BUILD_X1(q0)
    __syncthreads();
    #pragma unroll
    for (int rt = 0; rt < 8; ++rt) {
      const _Float16* ap = x1 + (rt*16 + m16)*72 + quad*8;
      half8 a0 = *(const half8*)(ap);
      half8 a1 = *(const half8*)(ap + 32);
      floatx4 acc = {0.f,0.f,0.f,0.f};
      acc = __builtin_amdgcn_mfma_f32_16x16x32_f16(a0, b1f0, acc, 0,0,0);
      acc = __builtin_amdgcn_mfma_f32_16x16x32_f16(a1, b1f1, acc, 0,0,0);
      #pragma unroll
      for (int rg = 0; rg < 4; ++rg) {
        float h = acc[rg] + b1c;
        float v = fmaxf(fmaf(h, sc1, sh1), 0.f);
        x2[(rt*16 + quad*4 + rg)*72 + col1] = (_Float16)v;
      }
    }
    __syncthreads();
    float mxA=0.f, mnA=0.f, mxB=0.f, mnB=0.f;
    #pragma unroll
    for (int rt = 0; rt < 8; ++rt) {
      const _Float16* ap = x2 + (rt*16 + m16)*72 + quad*8;
      half8 a0 = *(const half8*)(ap);
      half8 a1 = *(const half8*)(ap + 32);
      floatx4 accA = {0.f,0.f,0.f,0.f}, accB = {0.f,0.f,0.f,0.f};
      accA = __builtin_amdgcn_mfma_f32_16x16x32_f16(a0, b2A0, accA, 0,0,0);
      accA = __builtin_amdgcn_mfma_f32_16x16x32_f16(a1, b2A1, accA, 0,0,0);
      accB = __builtin_amdgcn_mfma_f32_16x16x32_f16(a0, b2B0, accB, 0,0,0);
      accB = __builtin_amdgcn_mfma_f32_16x16x32_f16(a1, b2B1, accB, 0,0,0);
      float hA0 = accA[0]+b2a, hA1 = accA[1]+b2a, hA2 = accA[2]+b2a, hA3 = accA[3]+b2a;
      float hB0 = accB[0]+b2b, hB1 = accB[1]+b2b, hB2 = accB[2]+b2b, hB3 = accB[3]+b2b;
      sA += hA0+hA1+hA2+hA3;
      ssA = fmaf(hA0,hA0, fmaf(hA1,hA1, fmaf(hA2,hA2, fmaf(hA3,hA3, ssA))));
      sB += hB0+hB1+hB2+hB3;
      ssB = fmaf(hB0,hB0, fmaf(hB1,hB1, fmaf(hB2,hB2, fmaf(hB3,hB3, ssB))));
      float m4A = fmaxf(fmaxf(hA0,hA1), fmaxf(hA2,hA3));
      float n4A = fminf(fminf(hA0,hA1), fminf(hA2,hA3));
      float m4B = fmaxf(fmaxf(hB0,hB1), fmaxf(hB2,hB3));
      float n4B = fminf(fminf(hB0,hB1), fminf(hB2,hB3));
      if ((rt & 1) == 0) { mxA=m4A; mnA=n4A; mxB=m4B; mnB=n4B; }
      else {
        mxA=fmaxf(mxA,m4A); mnA=fminf(mnA,n4A);
        mxB=fmaxf(mxB,m4B); mnB=fminf(mnB,n4B);
        mxA=fmaxf(mxA,__shfl_xor(mxA,16)); mxA=fmaxf(mxA,__shfl_xor(mxA,32));
        mnA=fminf(mnA,__shfl_xor(mnA,16)); mnA=fminf(mnA,__shfl_xor(mnA,32));
        mxB=fmaxf(mxB,__shfl_xor(mxB,16)); mxB=fmaxf(mxB,__shfl_xor(mxB,32));
        mnB=fminf(mnB,__shfl_xor(mnB,16)); mnB=fminf(mnB,__shfl_xor(mnB,32));
        if (quad == 0) {
          int qid = q0 + (rt >> 1);
          Mmax[(size_t)qid*128 + colA] = mxA;  Mmin[(size_t)qid*128 + colA] = mnA;
          Mmax[(size_t)qid*128 + colB] = mxB;  Mmin[(size_t)qid*128 + colB] = mnB;
        }
      }
    }
    __syncthreads();
  }
  sA += __shfl_xor(sA,16); sA += __shfl_xor(sA,32);
  ssA += __shfl_xor(ssA,16); ssA += __shfl_xor(ssA,32);
  sB += __shfl_xor(sB,16); sB += __shfl_xor(sB,32);
  ssB += __shfl_xor(ssB,16); ssB += __shfl_xor(ssB,32);
  if (quad == 0) {
    p2[blockIdx.x*256 + colA]        = sA;
    p2[blockIdx.x*256 + 128 + colA]  = ssA;
    p2[blockIdx.x*256 + colB]        = sB;
    p2[blockIdx.x*256 + 128 + colB]  = ssB;
  }
}

// ---------------------------------------------------------------------------
// K7: out = relu(affine2(max-or-min)); float4.
// ---------------------------------------------------------------------------
__global__ __launch_bounds__(256) void k_out(
    const float* __restrict__ Mmax, const float* __restrict__ Mmin,
    const float* __restrict__ par, float* __restrict__ out) {
  int t = blockIdx.x*256 + threadIdx.x;
  int seg = t & 31;                       // 128 channels / 4
  float4 sc = ((const float4*)(par+256))[seg];
  float4 sh = ((const float4*)(par+384))[seg];
  float4 mx = ((const float4*)Mmax)[t];
  float4 mn = ((const float4*)Mmin)[t];
  float4 o;
  o.x = fmaxf(fmaf(sc.x >= 0.f ? mx.x : mn.x, sc.x, sh.x), 0.f);
  o.y = fmaxf(fmaf(sc.y >= 0.f ? mx.y : mn.y, sc.y, sh.y), 0.f);
  o.z = fmaxf(fmaf(sc.z >= 0.f ? mx.z : mn.z, sc.z, sh.z), 0.f);
  o.w = fmaxf(fmaf(sc.w >= 0.f ? mx.w : mn.w, sc.w, sh.w), 0.f);
  ((float4*)out)[t] = o;
}

// ---------------------------------------------------------------------------
extern "C" void kernel_launch(void* const* d_in, const int* in_sizes, int n_in,
                              void* d_out, int out_size, void* d_ws, size_t ws_size,
                              hipStream_t stream) {
  const float* xyz    = (const float*)d_in[0];
  const float* points = (const float*)d_in[1];
  const float* W0     = (const float*)d_in[2];
  const float* b0     = (const float*)d_in[3];
  const float* g0     = (const float*)d_in[4];
  const float* beta0  = (const float*)d_in[5];
  const float* W1     = (const float*)d_in[6];
  const float* b1     = (const float*)d_in[7];
  const float* g1     = (const float*)d_in[8];
  const float* beta1  = (const float*)d_in[9];
  const float* W2     = (const float*)d_in[10];
  const float* b2     = (const float*)d_in[11];
  const float* g2     = (const float*)d_in[12];
  const float* beta2  = (const float*)d_in[13];

  char* ws = (char*)d_ws;
  float*     xyz4 = (float*)(ws + OFF_XYZ4);
  float*     Qb   = (float*)(ws + OFF_Q);
  float*     Rb   = (float*)(ws + OFF_R);
  int*       idxb = (int*)  (ws + OFF_IDX);
  _Float16*  W1h  = (_Float16*)(ws + OFF_W1H);
  _Float16*  W2h  = (_Float16*)(ws + OFF_W2H);
  float*     q0   = (float*)(ws + OFF_Q0);
  float*     q1   = (float*)(ws + OFF_Q1);
  float*     q2   = (float*)(ws + OFF_Q2);
  float*     p0b  = (float*)(ws + OFF_P0BIG);   // aliases Mmax (dead til k_l2)
  float*     p1   = (float*)(ws + OFF_P1);
  float*     p2   = (float*)(ws + OFF_P2);
  float*     par  = (float*)(ws + OFF_PAR);
  float*     Mmax = (float*)(ws + OFF_MMAX);
  float*     Mmin = (float*)(ws + OFF_MMIN);
  _Float16*  h1p  = (_Float16*)(ws + OFF_H1);
  float*     out  = (float*)d_out;

  const bool big = (ws_size >= WS_NEED);   // h1-staging fast path fits?

  hipLaunchKernelGGL(k_prep,  dim3(NQ/16 + 32), dim3(256), 0, stream,
                     xyz, points, W0, b0, W1, W2, xyz4, Qb, Rb, W1h, W2h);
  hipLaunchKernelGGL(k_knn,   dim3(NQ/4), dim3(256), 0, stream, xyz4, idxb, Rb, Qb, p0b);
  hipLaunchKernelGGL((k_redg<128,128>), dim3(64), dim3(256), 0, stream, p0b, q0);
  hipLaunchKernelGGL((k_fin<64>),   dim3(1), dim3(64),  0, stream, q0, 64, g0, beta0, par, 0);
  if (big) {
    hipLaunchKernelGGL((k_l1<true>),  dim3(1024), dim3(256), 0, stream,
                       Rb, Qb, idxb, W1h, b1, par, p1, h1p);
  } else {
    hipLaunchKernelGGL((k_l1<false>), dim3(1024), dim3(256), 0, stream,
                       Rb, Qb, idxb, W1h, b1, par, p1, h1p);
  }
  hipLaunchKernelGGL((k_redg<128,16>),  dim3(64), dim3(256), 0, stream, p1, q1);
  hipLaunchKernelGGL((k_fin<64>),   dim3(1), dim3(64),  0, stream, q1, 64, g1, beta1, par, 128);
  if (big) {
    hipLaunchKernelGGL(k_l2f, dim3(1024), dim3(256), 0, stream,
                       h1p, W2h, b2, par, p2, Mmax, Mmin);
  } else {
    hipLaunchKernelGGL(k_l2,  dim3(1024), dim3(256), 0, stream,
                       Rb, Qb, idxb, W1h, W2h, b1, b2, par, p2, Mmax, Mmin);
  }
  hipLaunchKernelGGL((k_redg<256,16>),  dim3(64), dim3(256), 0, stream, p2, q2);
  hipLaunchKernelGGL((k_fin<64>),   dim3(1), dim3(128), 0, stream, q2, 128, g2, beta2, par, 256);
  hipLaunchKernelGGL(k_out,   dim3(out_size/1024), dim3(256), 0, stream, Mmax, Mmin, par, out);
}

// Round 9
// 392.360 us; speedup vs baseline: 1.1096x; 1.1096x over previous
//
#include <hip/hip_runtime.h>

// ---------------------------------------------------------------------------
// PointNet++ set-abstraction block on MI355X.
// B=8, N=4096, K=32, D=64; out [B,N,128] fp32.
//  - layer0 linear decomposition: h0_pre = R[j] - Q[n]
//  - BN training-mode stats via per-block partials + k_redg/k_fin finalize
//  - layers 1/2 as fp16 MFMA (16x16x32) with fp32 accum
//  - max over K commutes with monotone BN affine: store max&min of h2 only
//  - kNN selection: R7-proven chunked pair-insertion (+R14 full-range tau).
//  - R17: h1-staging REVERTED (R16 refuted: BUILD_X1's gather hits L2-resident
//    R (8.4MB) -- replacing it with a 128MB HBM round-trip + halved k_l1
//    occupancy (36KB LDS) cost +37us net. Gathers from cache-resident arrays
//    are not materialization candidates.) Back to R15's proven k_l1/k_l2.
//    Kept from R16: k_prep at 16 points/block (W0 LDS stage amortized 4x,
//    math bit-identical) -- isolated this round.
//  - R15: all BN partial reductions via k_redg(64 blocks) + k_fin<64>.
//  - R12: k_fin partial count is a COMPILE-TIME template bound.
//  - R11: stats0 fused into k_knn epilogue; p0big aliases Mmax.
// ---------------------------------------------------------------------------

using half4  = __attribute__((ext_vector_type(4))) _Float16;
using half8  = __attribute__((ext_vector_type(8))) _Float16;
using floatx4 = __attribute__((ext_vector_type(4))) float;

#define NB 8
#define NP 4096
#define NQ (NB*NP)          // 32768 points / queries
#define CNT_INV (1.0f/1048576.0f)   // 1/(B*N*K), exact power of two

// ---- workspace layout (bytes) ----
#define OFF_XYZ4  0ull
#define OFF_Q     (OFF_XYZ4 + (size_t)NQ*4*4)       // xyz4: x,y,z,|x|^2
#define OFF_R     (OFF_Q    + (size_t)NQ*64*4)
#define OFF_IDX   (OFF_R    + (size_t)NQ*64*4)
#define OFF_W1H   (OFF_IDX  + (size_t)NQ*32*4)
#define OFF_W2H   (OFF_W1H  + 4096*2)
#define OFF_P0    (OFF_W2H  + 8192*2)               // q0/q1/q2 reduced partials
#define OFF_P1    (OFF_P0   + (size_t)1024*128*4)
#define OFF_P2    (OFF_P1   + (size_t)1024*128*4)
#define OFF_PAR   (OFF_P2   + (size_t)1024*256*4)
#define OFF_MMAX  (OFF_PAR  + 512*4)
#define OFF_MMIN  (OFF_MMAX + (size_t)NQ*128*4)
// p0big (8192*128 floats = 4MB) aliases Mmax: consumed by k_redg before k_l2
// writes Mmax. q0/q1/q2 live inside the P0 region.
#define OFF_P0BIG OFF_MMAX
#define OFF_Q0    OFF_P0
#define OFF_Q1    (OFF_P0 + (size_t)64*128*4)
#define OFF_Q2    (OFF_P0 + (size_t)2*64*128*4)

// ---------------------------------------------------------------------------
// K0: per-point prep, 16 points/block (+ fused W1/W2 fp16 cast in trailing
// blocks). W0 LDS staging amortized over 16 points; math bit-identical.
// ---------------------------------------------------------------------------
__global__ __launch_bounds__(256) void k_prep(
    const float* __restrict__ xyz, const float* __restrict__ points,
    const float* __restrict__ W0, const float* __restrict__ b0,
    const float* __restrict__ W1, const float* __restrict__ W2,
    float* __restrict__ xyz4, float* __restrict__ Q, float* __restrict__ R,
    _Float16* __restrict__ W1h, _Float16* __restrict__ W2h) {
  if (blockIdx.x >= NQ/16) {   // fused k_cast
    int t = (blockIdx.x - NQ/16)*256 + threadIdx.x;
    if (t < 4096) W1h[t] = (_Float16)W1[t];
    if (t < 8192) W2h[t] = (_Float16)W2[t];
    return;
  }
  __shared__ float w0s[64*67];
  for (int i = threadIdx.x; i < 64*67; i += 256) w0s[i] = W0[i];
  __syncthreads();
  int o = threadIdx.x & 63;
  const float* wr = w0s + o*67;
  #pragma unroll
  for (int pl = 0; pl < 4; ++pl) {
    int p = blockIdx.x*16 + pl*4 + (threadIdx.x >> 6);
    float x = xyz[p*3+0], y = xyz[p*3+1], z = xyz[p*3+2];
    float q = wr[0]*x + wr[1]*y + wr[2]*z;
    float r = b0[o] + q;
    const float4* pp4 = (const float4*)(points + (size_t)p*64);
    #pragma unroll
    for (int c4 = 0; c4 < 16; ++c4) {
      float4 pv = pp4[c4];
      r = fmaf(wr[3+4*c4+0], pv.x, r);
      r = fmaf(wr[3+4*c4+1], pv.y, r);
      r = fmaf(wr[3+4*c4+2], pv.z, r);
      r = fmaf(wr[3+4*c4+3], pv.w, r);
    }
    Q[(size_t)p*64 + o] = q;
    R[(size_t)p*64 + o] = r;
    if (o == 0) {
      float sq = fmaf(x,x, fmaf(y,y, z*z));
      xyz4[p*4+0]=x; xyz4[p*4+1]=y; xyz4[p*4+2]=z; xyz4[p*4+3]=sq;
    }
  }
}

// ---------------------------------------------------------------------------
// K1: exact kNN (R7 selection, R14 full-range tau first) + fused stats0.
// ---------------------------------------------------------------------------
__device__ __forceinline__ unsigned fmap(float f) {
  unsigned u = __float_as_uint(f);
  return u ^ ((unsigned)((int)u >> 31) | 0x80000000u);
}

#define INSERT_ROUND(uu, jj)                                                  \
  {                                                                           \
    unsigned long long ball = __ballot((uu) <= utau && (uu) < thr);           \
    while (ball) {                                                            \
      int src = __ffsll(ball) - 1;                                            \
      ball &= ball - 1;                                                       \
      unsigned cu = (unsigned)__builtin_amdgcn_readlane((int)(uu), src);      \
      int cj = __builtin_amdgcn_readlane((jj), src);                          \
      if (cu < thr) {                                                         \
        unsigned long long m = __ballot(lane < 32 && ku < cu);                \
        int pos = __popcll(m);                                                \
        unsigned ku_up = __shfl_up(ku, 1);                                    \
        int jv_up = __shfl_up(jv, 1);                                         \
        if (lane < 32) {                                                      \
          if (lane > pos)      { ku = ku_up; jv = jv_up; }                    \
          else if (lane == pos){ ku = cu;    jv = cj;    }                    \
        }                                                                     \
        thr = (unsigned)__builtin_amdgcn_readlane((int)ku, 31);               \
      }                                                                       \
    }                                                                         \
  }

__global__ __launch_bounds__(256, 6) void k_knn(
    const float* __restrict__ xyz4, int* __restrict__ idxb,
    const float* __restrict__ R, const float* __restrict__ Q,
    float* __restrict__ p0) {
  const int lane = threadIdx.x & 63;
  const int w = threadIdx.x >> 6;
  const int qid = blockIdx.x * 4 + w;
  const int b = qid >> 12;
  const float4* xb = (const float4*)xyz4 + (size_t)b * NP;
  const float4 qv = xb[qid & (NP-1)];
  int* op = idxb + (size_t)qid * 32;

  // R14: min-only pass over chunks 32..63 FIRST (before dvA exists).
  float mn = __uint_as_float(0x7F800000u);
  {
    float mn1 = mn, mn2 = mn, mn3 = mn;
    #pragma unroll 4
    for (int c = 32; c < 64; c += 4) {
      float4 a0 = xb[(c+0)*64 + lane];
      float4 a1 = xb[(c+1)*64 + lane];
      float4 a2 = xb[(c+2)*64 + lane];
      float4 a3 = xb[(c+3)*64 + lane];
      float d0 = fmaf(-2.0f, fmaf(qv.x,a0.x, fmaf(qv.y,a0.y, qv.z*a0.z)), qv.w + a0.w);
      float d1 = fmaf(-2.0f, fmaf(qv.x,a1.x, fmaf(qv.y,a1.y, qv.z*a1.z)), qv.w + a1.w);
      float d2 = fmaf(-2.0f, fmaf(qv.x,a2.x, fmaf(qv.y,a2.y, qv.z*a2.z)), qv.w + a2.w);
      float d3 = fmaf(-2.0f, fmaf(qv.x,a3.x, fmaf(qv.y,a3.y, qv.z*a3.z)), qv.w + a3.w);
      mn = fminf(mn, d0); mn1 = fminf(mn1, d1);
      mn2 = fminf(mn2, d2); mn3 = fminf(mn3, d3);
    }
    mn = fminf(fminf(mn, mn1), fminf(mn2, mn3));
  }

  float dvA[32];
  #pragma unroll
  for (int c = 0; c < 32; ++c) {
    float4 cd = xb[c*64 + lane];
    float dot = fmaf(qv.x, cd.x, fmaf(qv.y, cd.y, qv.z*cd.z));
    float d   = fmaf(-2.0f, dot, qv.w + cd.w);
    dvA[c] = d;
    mn = fminf(mn, d);
  }

  const unsigned mu = fmap(mn);
  unsigned lo = 0u, hi = 0xFFFFFFFFu;
  for (int it = 0; it < 32; ++it) {
    unsigned mid = lo + ((hi - lo) >> 1);
    int cnt = __popcll(__ballot(mu <= mid));
    if (cnt >= 32) hi = mid; else lo = mid + 1;
  }
  const unsigned utau = hi;

  unsigned ku = 0xFFFFFFFFu;
  int jv = 0;
  unsigned thr = 0xFFFFFFFFu;
  #pragma unroll
  for (int c = 0; c < 32; ++c) {
    unsigned u = fmap(dvA[c]);
    int j = c*64 + lane;
    INSERT_ROUND(u, j)
  }
  #pragma unroll 8
  for (int c = 32; c < 64; ++c) {
    float4 cd = xb[c*64 + lane];
    float dot = fmaf(qv.x, cd.x, fmaf(qv.y, cd.y, qv.z*cd.z));
    float d   = fmaf(-2.0f, dot, qv.w + cd.w);
    unsigned u = fmap(d);
    int j = c*64 + lane;
    INSERT_ROUND(u, j)
  }
  if (lane < 32) op[lane] = jv;

  // ---- fused stats0 epilogue: v = R[j][c]-Q[qid][c], c = lane ----
  const float* Rb2 = R + (size_t)(qid & ~(NP-1))*64;
  const float  qc  = Q[(size_t)qid*64 + lane];
  float s = 0.f, ss = 0.f;
  #pragma unroll 8
  for (int k = 0; k < 32; ++k) {
    int j = __shfl(jv, k);                       // broadcast from lane k
    float v = Rb2[(size_t)j*64 + lane] - qc;     // coalesced 256B row
    s += v; ss = fmaf(v, v, ss);
  }
  __shared__ float red[4][128];
  red[w][lane]      = s;
  red[w][64 + lane] = ss;
  __syncthreads();
  if (w == 0) {
    float S  = red[0][lane]    + red[1][lane]    + red[2][lane]    + red[3][lane];
    float SS = red[0][64+lane] + red[1][64+lane] + red[2][64+lane] + red[3][64+lane];
    p0[(size_t)blockIdx.x*128 + lane]      = S;
    p0[(size_t)blockIdx.x*128 + 64 + lane] = SS;
  }
}

// ---------------------------------------------------------------------------
// K2b (R15): generic tree reduction of partial rows. 64 output rows.
// ---------------------------------------------------------------------------
template<int W, int RPB>
__global__ __launch_bounds__(256) void k_redg(
    const float* __restrict__ pin, float* __restrict__ pout) {
  constexpr int G   = 256 / W;   // thread groups per block
  constexpr int RPG = RPB / G;   // rows per group
  int r   = blockIdx.x;
  int col = threadIdx.x % W;
  int g   = threadIdx.x / W;
  const float* base = pin + ((size_t)r*RPB + (size_t)g*RPG)*W + col;
  float s = 0.f;
  #pragma unroll
  for (int i = 0; i < RPG; ++i) s += base[(size_t)i*W];
  if constexpr (G == 1) {
    pout[(size_t)r*W + col] = s;
  } else {
    __shared__ float rr[G][W];
    rr[g][col] = s;
    __syncthreads();
    if (threadIdx.x < W) {
      float t = rr[0][threadIdx.x];
      #pragma unroll
      for (int gg = 1; gg < G; ++gg) t += rr[gg][threadIdx.x];
      pout[(size_t)r*W + threadIdx.x] = t;
    }
  }
}

// ---------------------------------------------------------------------------
// K3: finalize BN stats -> affine params (scale, shift) at par[poff..].
// ---------------------------------------------------------------------------
template<int NPARTS>
__global__ void k_fin(const float* __restrict__ part, int C,
                      const float* __restrict__ g, const float* __restrict__ beta,
                      float* __restrict__ par, int poff) {
  int o = threadIdx.x;
  float S = 0.f, SS = 0.f;
  #pragma unroll
  for (int s = 0; s < NPARTS; ++s) {
    S  += part[s*2*C + o];
    SS += part[s*2*C + C + o];
  }
  float mu  = S * CNT_INV;
  float var = SS * CNT_INV - mu*mu;
  float sc  = g[o] * rsqrtf(var + 1e-5f);
  par[poff + o]     = sc;
  par[poff + C + o] = beta[o] - mu*sc;
}

// ---------------------------------------------------------------------------
// Phase-A helper macro: vectorized x1 build (float4 gather -> half4 LDS)
// ---------------------------------------------------------------------------
#define BUILD_X1(q0)                                                          \
  {                                                                           \
    int qid = (q0) + aql;                                                     \
    const float* Rb = R + (size_t)(qid & ~4095)*64;                           \
    const int* ix = idxb + (size_t)qid*32;                                    \
    float4 Q4 = ((const float4*)(Q + (size_t)qid*64))[aseg];                  \
    float qx = fmaf(-Q4.x, asc.x, ash.x);                                     \
    float qy = fmaf(-Q4.y, asc.y, ash.y);                                     \
    float qz = fmaf(-Q4.z, asc.z, ash.z);                                     \
    float qw = fmaf(-Q4.w, asc.w, ash.w);                                     \
    _Pragma("unroll")                                                         \
    for (int i = 0; i < 8; ++i) {                                             \
      int k = arg + (i<<2);                                                   \
      int j = ix[k];                                                          \
      float4 R4 = ((const float4*)(Rb + (size_t)j*64))[aseg];                 \
      float v0 = fmaxf(fmaf(R4.x, asc.x, qx), 0.f);                           \
      float v1 = fmaxf(fmaf(R4.y, asc.y, qy), 0.f);                           \
      float v2 = fmaxf(fmaf(R4.z, asc.z, qz), 0.f);                           \
      float v3 = fmaxf(fmaf(R4.w, asc.w, qw), 0.f);                           \
      half4 hv = {(_Float16)v0, (_Float16)v1, (_Float16)v2, (_Float16)v3};    \
      *(half4*)(x1 + (aql*32 + k)*72 + aseg*4) = hv;                          \
    }                                                                         \
  }

// ---------------------------------------------------------------------------
// K4: layer1 via fp16 MFMA; emit stats1 partials.
// ---------------------------------------------------------------------------
__global__ __launch_bounds__(256) void k_l1(
    const float* __restrict__ R, const float* __restrict__ Q,
    const int* __restrict__ idxb, const _Float16* __restrict__ W1h,
    const float* __restrict__ b1, const float* __restrict__ par,
    float* __restrict__ p1) {
  __shared__ __align__(16) _Float16 x1[128*72];
  int o = threadIdx.x & 63, wg = threadIdx.x >> 6;
  int m16 = o & 15, quad = o >> 4;
  const int aql = threadIdx.x >> 6;
  const int arg = (threadIdx.x >> 4) & 3;
  const int aseg = threadIdx.x & 15;
  const float4 asc = ((const float4*)par)[aseg];
  const float4 ash = ((const float4*)(par+64))[aseg];
  int col = wg*16 + m16;
  half8 bf0 = *(const half8*)(W1h + col*64 + quad*8);
  half8 bf1 = *(const half8*)(W1h + col*64 + 32 + quad*8);
  float b1c = b1[col];
  float s = 0.f, ss = 0.f;

  for (int gi = 0; gi < 8; ++gi) {
    int q0 = (blockIdx.x*8 + gi) * 4;
    BUILD_X1(q0)
    __syncthreads();
    #pragma unroll
    for (int rt = 0; rt < 8; ++rt) {
      const _Float16* ap = x1 + (rt*16 + m16)*72 + quad*8;
      half8 a0 = *(const half8*)(ap);
      half8 a1 = *(const half8*)(ap + 32);
      floatx4 acc = {0.f,0.f,0.f,0.f};
      acc = __builtin_amdgcn_mfma_f32_16x16x32_f16(a0, bf0, acc, 0,0,0);
      acc = __builtin_amdgcn_mfma_f32_16x16x32_f16(a1, bf1, acc, 0,0,0);
      #pragma unroll
      for (int rg = 0; rg < 4; ++rg) {
        float h = acc[rg] + b1c;
        s += h; ss = fmaf(h, h, ss);
      }
    }
    __syncthreads();
  }
  s  += __shfl_xor(s, 16);  s  += __shfl_xor(s, 32);
  ss += __shfl_xor(ss, 16); ss += __shfl_xor(ss, 32);
  if (quad == 0) {
    p1[blockIdx.x*128 + col]      = s;
    p1[blockIdx.x*128 + 64 + col] = ss;
  }
}

// ---------------------------------------------------------------------------
// K6: layer1 (recompute) -> bn1+relu -> layer2 MFMA -> stats2 + max/min
// ---------------------------------------------------------------------------
__global__ __launch_bounds__(256) void k_l2(
    const float* __restrict__ R, const float* __restrict__ Q,
    const int* __restrict__ idxb, const _Float16* __restrict__ W1h,
    const _Float16* __restrict__ W2h, const float* __restrict__ b1,
    const float* __restrict__ b2, const float* __restrict__ par,
    float* __restrict__ p2, float* __restrict__ Mmax, float* __restrict__ Mmin) {
  __shared__ __align__(16) _Float16 x1[128*72];
  __shared__ __align__(16) _Float16 x2[128*72];
  int o = threadIdx.x & 63, wg = threadIdx.x >> 6;
  int m16 = o & 15, quad = o >> 4;
  const int aql = threadIdx.x >> 6;
  const int arg = (threadIdx.x >> 4) & 3;
  const int aseg = threadIdx.x & 15;
  const float4 asc = ((const float4*)par)[aseg];
  const float4 ash = ((const float4*)(par+64))[aseg];
  int col1 = wg*16 + m16;
  float sc1 = par[128 + col1], sh1 = par[192 + col1];
  half8 b1f0 = *(const half8*)(W1h + col1*64 + quad*8);
  half8 b1f1 = *(const half8*)(W1h + col1*64 + 32 + quad*8);
  float b1c = b1[col1];
  int colA = wg*16 + m16, colB = 64 + wg*16 + m16;
  half8 b2A0 = *(const half8*)(W2h + colA*64 + quad*8);
  half8 b2A1 = *(const half8*)(W2h + colA*64 + 32 + quad*8);
  half8 b2B0 = *(const half8*)(W2h + colB*64 + quad*8);
  half8 b2B1 = *(const half8*)(W2h + colB*64 + 32 + quad*8);
  float b2a = b2[colA], b2b = b2[colB];
  float sA=0.f, ssA=0.f, sB=0.f, ssB=0.f;

  for (int gi = 0; gi < 8; ++gi) {
    int q0 = (blockIdx.x*8 + gi) * 4;
    BUILD_X1(q0)
    __syncthreads();
    #pragma unroll
    for (int rt = 0; rt < 8; ++rt) {
      const _Float16* ap = x1 + (rt*16 + m16)*72 + quad*8;
      half8 a0 = *(const half8*)(ap);
      half8 a1 = *(const half8*)(ap + 32);
      floatx4 acc = {0.f,0.f,0.f,0.f};
      acc = __builtin_amdgcn_mfma_f32_16x16x32_f16(a0, b1f0, acc, 0,0,0);
      acc = __builtin_amdgcn_mfma_f32_16x16x32_f16(a1, b1f1, acc, 0,0,0);
      #pragma unroll
      for (int rg = 0; rg < 4; ++rg) {
        float h = acc[rg] + b1c;
        float v = fmaxf(fmaf(h, sc1, sh1), 0.f);
        x2[(rt*16 + quad*4 + rg)*72 + col1] = (_Float16)v;
      }
    }
    __syncthreads();
    float mxA=0.f, mnA=0.f, mxB=0.f, mnB=0.f;
    #pragma unroll
    for (int rt = 0; rt < 8; ++rt) {
      const _Float16* ap = x2 + (rt*16 + m16)*72 + quad*8;
      half8 a0 = *(const half8*)(ap);
      half8 a1 = *(const half8*)(ap + 32);
      floatx4 accA = {0.f,0.f,0.f,0.f}, accB = {0.f,0.f,0.f,0.f};
      accA = __builtin_amdgcn_mfma_f32_16x16x32_f16(a0, b2A0, accA, 0,0,0);
      accA = __builtin_amdgcn_mfma_f32_16x16x32_f16(a1, b2A1, accA, 0,0,0);
      accB = __builtin_amdgcn_mfma_f32_16x16x32_f16(a0, b2B0, accB, 0,0,0);
      accB = __builtin_amdgcn_mfma_f32_16x16x32_f16(a1, b2B1, accB, 0,0,0);
      float hA0 = accA[0]+b2a, hA1 = accA[1]+b2a, hA2 = accA[2]+b2a, hA3 = accA[3]+b2a;
      float hB0 = accB[0]+b2b, hB1 = accB[1]+b2b, hB2 = accB[2]+b2b, hB3 = accB[3]+b2b;
      sA += hA0+hA1+hA2+hA3;
      ssA = fmaf(hA0,hA0, fmaf(hA1,hA1, fmaf(hA2,hA2, fmaf(hA3,hA3, ssA))));
      sB += hB0+hB1+hB2+hB3;
      ssB = fmaf(hB0,hB0, fmaf(hB1,hB1, fmaf(hB2,hB2, fmaf(hB3,hB3, ssB))));
      float m4A = fmaxf(fmaxf(hA0,hA1), fmaxf(hA2,hA3));
      float n4A = fminf(fminf(hA0,hA1), fminf(hA2,hA3));
      float m4B = fmaxf(fmaxf(hB0,hB1), fmaxf(hB2,hB3));
      float n4B = fminf(fminf(hB0,hB1), fminf(hB2,hB3));
      if ((rt & 1) == 0) { mxA=m4A; mnA=n4A; mxB=m4B; mnB=n4B; }
      else {
        mxA=fmaxf(mxA,m4A); mnA=fminf(mnA,n4A);
        mxB=fmaxf(mxB,m4B); mnB=fminf(mnB,n4B);
        mxA=fmaxf(mxA,__shfl_xor(mxA,16)); mxA=fmaxf(mxA,__shfl_xor(mxA,32));
        mnA=fminf(mnA,__shfl_xor(mnA,16)); mnA=fminf(mnA,__shfl_xor(mnA,32));
        mxB=fmaxf(mxB,__shfl_xor(mxB,16)); mxB=fmaxf(mxB,__shfl_xor(mxB,32));
        mnB=fminf(mnB,__shfl_xor(mnB,16)); mnB=fminf(mnB,__shfl_xor(mnB,32));
        if (quad == 0) {
          int qid = q0 + (rt >> 1);
          Mmax[(size_t)qid*128 + colA] = mxA;  Mmin[(size_t)qid*128 + colA] = mnA;
          Mmax[(size_t)qid*128 + colB] = mxB;  Mmin[(size_t)qid*128 + colB] = mnB;
        }
      }
    }
    __syncthreads();
  }
  sA += __shfl_xor(sA,16); sA += __shfl_xor(sA,32);
  ssA += __shfl_xor(ssA,16); ssA += __shfl_xor(ssA,32);
  sB += __shfl_xor(sB,16); sB += __shfl_xor(sB,32);
  ssB += __shfl_xor(ssB,16); ssB += __shfl_xor(ssB,32);
  if (quad == 0) {
    p2[blockIdx.x*256 + colA]        = sA;
    p2[blockIdx.x*256 + 128 + colA]  = ssA;
    p2[blockIdx.x*256 + colB]        = sB;
    p2[blockIdx.x*256 + 128 + colB]  = ssB;
  }
}

// ---------------------------------------------------------------------------
// K7: out = relu(affine2(max-or-min)); float4.
// ---------------------------------------------------------------------------
__global__ __launch_bounds__(256) void k_out(
    const float* __restrict__ Mmax, const float* __restrict__ Mmin,
    const float* __restrict__ par, float* __restrict__ out) {
  int t = blockIdx.x*256 + threadIdx.x;
  int seg = t & 31;                       // 128 channels / 4
  float4 sc = ((const float4*)(par+256))[seg];
  float4 sh = ((const float4*)(par+384))[seg];
  float4 mx = ((const float4*)Mmax)[t];
  float4 mn = ((const float4*)Mmin)[t];
  float4 o;
  o.x = fmaxf(fmaf(sc.x >= 0.f ? mx.x : mn.x, sc.x, sh.x), 0.f);
  o.y = fmaxf(fmaf(sc.y >= 0.f ? mx.y : mn.y, sc.y, sh.y), 0.f);
  o.z = fmaxf(fmaf(sc.z >= 0.f ? mx.z : mn.z, sc.z, sh.z), 0.f);
  o.w = fmaxf(fmaf(sc.w >= 0.f ? mx.w : mn.w, sc.w, sh.w), 0.f);
  ((float4*)out)[t] = o;
}

// ---------------------------------------------------------------------------
extern "C" void kernel_launch(void* const* d_in, const int* in_sizes, int n_in,
                              void* d_out, int out_size, void* d_ws, size_t ws_size,
                              hipStream_t stream) {
  const float* xyz    = (const float*)d_in[0];
  const float* points = (const float*)d_in[1];
  const float* W0     = (const float*)d_in[2];
  const float* b0     = (const float*)d_in[3];
  const float* g0     = (const float*)d_in[4];
  const float* beta0  = (const float*)d_in[5];
  const float* W1     = (const float*)d_in[6];
  const float* b1     = (const float*)d_in[7];
  const float* g1     = (const float*)d_in[8];
  const float* beta1  = (const float*)d_in[9];
  const float* W2     = (const float*)d_in[10];
  const float* b2     = (const float*)d_in[11];
  const float* g2     = (const float*)d_in[12];
  const float* beta2  = (const float*)d_in[13];

  char* ws = (char*)d_ws;
  float*     xyz4 = (float*)(ws + OFF_XYZ4);
  float*     Qb   = (float*)(ws + OFF_Q);
  float*     Rb   = (float*)(ws + OFF_R);
  int*       idxb = (int*)  (ws + OFF_IDX);
  _Float16*  W1h  = (_Float16*)(ws + OFF_W1H);
  _Float16*  W2h  = (_Float16*)(ws + OFF_W2H);
  float*     q0   = (float*)(ws + OFF_Q0);
  float*     q1   = (float*)(ws + OFF_Q1);
  float*     q2   = (float*)(ws + OFF_Q2);
  float*     p0b  = (float*)(ws + OFF_P0BIG);   // aliases Mmax (dead til k_l2)
  float*     p1   = (float*)(ws + OFF_P1);
  float*     p2   = (float*)(ws + OFF_P2);
  float*     par  = (float*)(ws + OFF_PAR);
  float*     Mmax = (float*)(ws + OFF_MMAX);
  float*     Mmin = (float*)(ws + OFF_MMIN);
  float*     out  = (float*)d_out;

  hipLaunchKernelGGL(k_prep,  dim3(NQ/16 + 32), dim3(256), 0, stream,
                     xyz, points, W0, b0, W1, W2, xyz4, Qb, Rb, W1h, W2h);
  hipLaunchKernelGGL(k_knn,   dim3(NQ/4), dim3(256), 0, stream, xyz4, idxb, Rb, Qb, p0b);
  hipLaunchKernelGGL((k_redg<128,128>), dim3(64), dim3(256), 0, stream, p0b, q0);
  hipLaunchKernelGGL((k_fin<64>),   dim3(1), dim3(64),  0, stream, q0, 64, g0, beta0, par, 0);
  hipLaunchKernelGGL(k_l1,    dim3(1024), dim3(256), 0, stream, Rb, Qb, idxb, W1h, b1, par, p1);
  hipLaunchKernelGGL((k_redg<128,16>),  dim3(64), dim3(256), 0, stream, p1, q1);
  hipLaunchKernelGGL((k_fin<64>),   dim3(1), dim3(64),  0, stream, q1, 64, g1, beta1, par, 128);
  hipLaunchKernelGGL(k_l2,    dim3(1024), dim3(256), 0, stream, Rb, Qb, idxb, W1h, W2h, b1, b2, par, p2, Mmax, Mmin);
  hipLaunchKernelGGL((k_redg<256,16>),  dim3(64), dim3(256), 0, stream, p2, q2);
  hipLaunchKernelGGL((k_fin<64>),   dim3(1), dim3(128), 0, stream, q2, 128, g2, beta2, par, 256);
  hipLaunchKernelGGL(k_out,   dim3(out_size/1024), dim3(256), 0, stream, Mmax, Mmin, par, out);
}